// Round 2
// baseline (943.437 us; speedup 1.0000x reference)
//
#include <hip/hip_runtime.h>

// Problem constants (fixed by the reference): B=16, M=1024, V=4.
#define M_DIM 1024
#define M_SHIFT 10
#define BLOCK 256
#define UNROLL 8

// ws layout: acc[0..3] = tt, ss, it, is (double); acc[4] reinterpreted as
// completion counter (unsigned). All zeroed by on-stream memset each call.

__global__ void pose_loss_reduce(const float4* __restrict__ pred,
                                 const float4* __restrict__ gt,
                                 const int* __restrict__ Ms, int V, int B,
                                 long long N, double* __restrict__ acc,
                                 unsigned int* __restrict__ cnt,
                                 float* __restrict__ out)
{
    // cumulative start offsets of each view (V <= 8 supported)
    int cum[9];
    cum[0] = 0;
#pragma unroll
    for (int v = 0; v < 8; ++v) {
        int m = (v < V) ? Ms[v] : 0;
        cum[v + 1] = cum[v] + m;
    }

    float tt = 0.f, ss = 0.f, it = 0.f, is = 0.f;

    const long long stride = (long long)gridDim.x * BLOCK;
    long long idx = (long long)blockIdx.x * BLOCK + threadIdx.x;

    // Main unrolled loop: 16 independent dwordx4 loads in flight per wave.
    for (; idx + (UNROLL - 1) * stride < N; idx += UNROLL * stride) {
        float4 p[UNROLL], g[UNROLL];
#pragma unroll
        for (int u = 0; u < UNROLL; ++u) p[u] = pred[idx + u * stride];
#pragma unroll
        for (int u = 0; u < UNROLL; ++u) g[u] = gt[idx + u * stride];
#pragma unroll
        for (int u = 0; u < UNROLL; ++u) {
            long long id = idx + u * stride;
            int j = (int)(id & (M_DIM - 1));
            int i = (int)((id >> M_SHIFT) & (M_DIM - 1));
            float d0 = p[u].x - g[u].x, d1 = p[u].y - g[u].y;
            float d2 = p[u].z - g[u].z, d3 = p[u].w - g[u].w;
            float t = d0 * d0 + d1 * d1;
            float s = d2 * d2 + d3 * d3;
            int vi = 0, vj = 0;
#pragma unroll
            for (int v = 1; v < 8; ++v) {
                if (v < V) {
                    vi += (i >= cum[v]);
                    vj += (j >= cum[v]);
                }
            }
            float w = (vi != vj) ? 1.0f : 0.0f;
            tt += t;
            ss += s;
            it += t * w;
            is += s * w;
        }
    }
    // Tail
    for (; idx < N; idx += stride) {
        int j = (int)(idx & (M_DIM - 1));
        int i = (int)((idx >> M_SHIFT) & (M_DIM - 1));
        float4 p = pred[idx];
        float4 g = gt[idx];
        float d0 = p.x - g.x, d1 = p.y - g.y, d2 = p.z - g.z, d3 = p.w - g.w;
        float t = d0 * d0 + d1 * d1;
        float s = d2 * d2 + d3 * d3;
        int vi = 0, vj = 0;
#pragma unroll
        for (int v = 1; v < 8; ++v) {
            if (v < V) {
                vi += (i >= cum[v]);
                vj += (j >= cum[v]);
            }
        }
        float w = (vi != vj) ? 1.0f : 0.0f;
        tt += t; ss += s; it += t * w; is += s * w;
    }

    // 64-lane wave reduction
#pragma unroll
    for (int off = 32; off > 0; off >>= 1) {
        tt += __shfl_down(tt, off);
        ss += __shfl_down(ss, off);
        it += __shfl_down(it, off);
        is += __shfl_down(is, off);
    }

    __shared__ float l_tt[BLOCK / 64], l_ss[BLOCK / 64],
                     l_it[BLOCK / 64], l_is[BLOCK / 64];
    int wave = threadIdx.x >> 6;
    int lane = threadIdx.x & 63;
    if (lane == 0) {
        l_tt[wave] = tt; l_ss[wave] = ss;
        l_it[wave] = it; l_is[wave] = is;
    }
    __syncthreads();

    if (threadIdx.x == 0) {
        float a = 0.f, b = 0.f, c = 0.f, d = 0.f;
#pragma unroll
        for (int w = 0; w < BLOCK / 64; ++w) {
            a += l_tt[w]; b += l_ss[w]; c += l_it[w]; d += l_is[w];
        }
        atomicAdd(&acc[0], (double)a);
        atomicAdd(&acc[1], (double)b);
        atomicAdd(&acc[2], (double)c);
        atomicAdd(&acc[3], (double)d);

        __threadfence();  // make partials visible before signaling
        unsigned int old = atomicAdd(cnt, 1u);
        if (old == gridDim.x - 1) {
            // Last block: finalize. Read accumulators via atomic RMW to get
            // device-coherent values (plain loads could hit a stale local L2).
            double s_tt = atomicAdd(&acc[0], 0.0);
            double s_ss = atomicAdd(&acc[1], 0.0);
            double s_it = atomicAdd(&acc[2], 0.0);
            double s_is = atomicAdd(&acc[3], 0.0);

            long long sumsq = 0;
            for (int v = 0; v < V; ++v) {
                long long m = Ms[v];
                sumsq += m * m;
            }
            double diag = (double)sumsq * (double)B;
            double offd = ((double)M_DIM * (double)M_DIM - (double)sumsq) * (double)B;

            double li_t = (s_tt - s_it) / diag;
            double le_t = s_it / offd;
            double li_s = (s_ss - s_is) / diag;
            double le_s = s_is / offd;

            const double A_T = 0.5, A_S = 0.75, A_TS = 0.5;
            double lt = A_T * le_t + (1.0 - A_T) * li_t;
            double ls = A_S * le_s + (1.0 - A_S) * li_s;
            double loss = A_TS * lt + (1.0 - A_TS) * ls;

            out[0] = (float)li_t;
            out[1] = (float)le_t;
            out[2] = (float)li_s;
            out[3] = (float)le_s;
            out[4] = (float)lt;
            out[5] = (float)ls;
            out[6] = (float)loss;
        }
    }
}

extern "C" void kernel_launch(void* const* d_in, const int* in_sizes, int n_in,
                              void* d_out, int out_size, void* d_ws, size_t ws_size,
                              hipStream_t stream)
{
    const float* pred = (const float*)d_in[0];
    const float* gt   = (const float*)d_in[1];
    const int*   Ms   = (const int*)d_in[2];
    int V = in_sizes[2];

    long long total = (long long)in_sizes[0];            // B*M*M*4
    long long N     = total / 4;                         // float4 groups
    int B           = (int)(total / (4LL * M_DIM * M_DIM));

    double* acc = (double*)d_ws;
    unsigned int* cnt = (unsigned int*)(acc + 4);
    hipMemsetAsync(d_ws, 0, 5 * sizeof(double), stream); // acc + counter

    // One outer iteration per thread: grid*BLOCK*UNROLL == N when N==16M.
    long long want = (N + (long long)BLOCK * UNROLL - 1) / ((long long)BLOCK * UNROLL);
    int grid = (int)((want < 1) ? 1 : (want > 65535 ? 65535 : want));
    pose_loss_reduce<<<grid, BLOCK, 0, stream>>>(
        (const float4*)pred, (const float4*)gt, Ms, V, B, N, acc, cnt,
        (float*)d_out);
}

// Round 3
// 505.659 us; speedup vs baseline: 1.8658x; 1.8658x over previous
//
#include <hip/hip_runtime.h>

// Problem constants (fixed by the reference): B=16, M=1024, V=4.
#define M_DIM 1024
#define M_SHIFT 10
#define BLOCK 256
#define GRID 2048   // 8 blocks/CU x 256 CUs -> fully resident at low VGPR

// ws layout: part[GRID] float4 partials (tt, ss, it, is per block) = 32 KiB.

__global__ void pose_loss_partial(const float4* __restrict__ pred,
                                  const float4* __restrict__ gt,
                                  const int* __restrict__ Ms, int V,
                                  long long N, float4* __restrict__ part)
{
    // cumulative start offsets of each view (V <= 8 supported)
    int cum[9];
    cum[0] = 0;
#pragma unroll
    for (int v = 0; v < 8; ++v) {
        int m = (v < V) ? Ms[v] : 0;
        cum[v + 1] = cum[v] + m;
    }

    float tt = 0.f, ss = 0.f, it = 0.f, is = 0.f;

    const long long stride = (long long)gridDim.x * BLOCK;
    for (long long idx = (long long)blockIdx.x * BLOCK + threadIdx.x;
         idx < N; idx += stride) {
        int j = (int)(idx & (M_DIM - 1));
        int i = (int)((idx >> M_SHIFT) & (M_DIM - 1));

        float4 p = pred[idx];
        float4 g = gt[idx];
        float d0 = p.x - g.x, d1 = p.y - g.y, d2 = p.z - g.z, d3 = p.w - g.w;
        float t = d0 * d0 + d1 * d1;
        float s = d2 * d2 + d3 * d3;

        int vi = 0, vj = 0;
#pragma unroll
        for (int v = 1; v < 8; ++v) {
            if (v < V) {
                vi += (i >= cum[v]);
                vj += (j >= cum[v]);
            }
        }
        float w = (vi != vj) ? 1.0f : 0.0f;
        tt += t;
        ss += s;
        it += t * w;
        is += s * w;
    }

    // 64-lane wave reduction
#pragma unroll
    for (int off = 32; off > 0; off >>= 1) {
        tt += __shfl_down(tt, off);
        ss += __shfl_down(ss, off);
        it += __shfl_down(it, off);
        is += __shfl_down(is, off);
    }

    __shared__ float l_tt[BLOCK / 64], l_ss[BLOCK / 64],
                     l_it[BLOCK / 64], l_is[BLOCK / 64];
    int wave = threadIdx.x >> 6;
    int lane = threadIdx.x & 63;
    if (lane == 0) {
        l_tt[wave] = tt; l_ss[wave] = ss;
        l_it[wave] = it; l_is[wave] = is;
    }
    __syncthreads();
    if (threadIdx.x == 0) {
        float a = 0.f, b = 0.f, c = 0.f, d = 0.f;
#pragma unroll
        for (int w = 0; w < BLOCK / 64; ++w) {
            a += l_tt[w]; b += l_ss[w]; c += l_it[w]; d += l_is[w];
        }
        part[blockIdx.x] = make_float4(a, b, c, d);  // private slot: no contention
    }
}

__global__ void pose_loss_final(const float4* __restrict__ part, int nparts,
                                const int* __restrict__ Ms, int V, int B,
                                float* __restrict__ out)
{
    // One block of 256 threads; each sums nparts/256 slots, then reduces.
    double tt = 0.0, ss = 0.0, it = 0.0, is = 0.0;
    for (int k = threadIdx.x; k < nparts; k += BLOCK) {
        float4 q = part[k];
        tt += q.x; ss += q.y; it += q.z; is += q.w;
    }
#pragma unroll
    for (int off = 32; off > 0; off >>= 1) {
        tt += __shfl_down(tt, off);
        ss += __shfl_down(ss, off);
        it += __shfl_down(it, off);
        is += __shfl_down(is, off);
    }
    __shared__ double l_tt[BLOCK / 64], l_ss[BLOCK / 64],
                      l_it[BLOCK / 64], l_is[BLOCK / 64];
    int wave = threadIdx.x >> 6;
    int lane = threadIdx.x & 63;
    if (lane == 0) {
        l_tt[wave] = tt; l_ss[wave] = ss;
        l_it[wave] = it; l_is[wave] = is;
    }
    __syncthreads();
    if (threadIdx.x == 0) {
        double s_tt = 0, s_ss = 0, s_it = 0, s_is = 0;
#pragma unroll
        for (int w = 0; w < BLOCK / 64; ++w) {
            s_tt += l_tt[w]; s_ss += l_ss[w];
            s_it += l_it[w]; s_is += l_is[w];
        }
        long long sumsq = 0;
        for (int v = 0; v < V; ++v) {
            long long m = Ms[v];
            sumsq += m * m;
        }
        double diag = (double)sumsq * (double)B;
        double offd = ((double)M_DIM * (double)M_DIM - (double)sumsq) * (double)B;

        double li_t = (s_tt - s_it) / diag;
        double le_t = s_it / offd;
        double li_s = (s_ss - s_is) / diag;
        double le_s = s_is / offd;

        const double A_T = 0.5, A_S = 0.75, A_TS = 0.5;
        double lt = A_T * le_t + (1.0 - A_T) * li_t;
        double ls = A_S * le_s + (1.0 - A_S) * li_s;
        double loss = A_TS * lt + (1.0 - A_TS) * ls;

        out[0] = (float)li_t;
        out[1] = (float)le_t;
        out[2] = (float)li_s;
        out[3] = (float)le_s;
        out[4] = (float)lt;
        out[5] = (float)ls;
        out[6] = (float)loss;
    }
}

extern "C" void kernel_launch(void* const* d_in, const int* in_sizes, int n_in,
                              void* d_out, int out_size, void* d_ws, size_t ws_size,
                              hipStream_t stream)
{
    const float* pred = (const float*)d_in[0];
    const float* gt   = (const float*)d_in[1];
    const int*   Ms   = (const int*)d_in[2];
    int V = in_sizes[2];

    long long total = (long long)in_sizes[0];            // B*M*M*4
    long long N     = total / 4;                         // float4 groups
    int B           = (int)(total / (4LL * M_DIM * M_DIM));

    float4* part = (float4*)d_ws;                        // GRID slots, 32 KiB

    pose_loss_partial<<<GRID, BLOCK, 0, stream>>>(
        (const float4*)pred, (const float4*)gt, Ms, V, N, part);
    pose_loss_final<<<1, BLOCK, 0, stream>>>(part, GRID, Ms, V, B,
                                             (float*)d_out);
}